// Round 3
// baseline (10498.006 us; speedup 1.0000x reference)
//
#include <hip/hip_runtime.h>

// PositionCloser round 16: batch 4 sequences into the MFMA M-dimension.
// R15 evidence: MfmaUtil 49.4% == 32 MFMA x 16 cyc / 1030 cyc-per-step exactly
// -> the matrix pipe's per-SIMD occupancy is the bound, and 15/16 of every
// D-tile is wasted (all A rows identical, only acc[0] read). Fix: A rows
// 4q..4q+3 hold seq q's h (q=0..3); C/D layout (m89: col=lane&15,
// row=4*(lane>>4)+reg) makes acc[0] at lane l = preact[16t+(l&15)] of seq
// l>>4. Same 32 MFMAs now serve 4 sequences -> 128 MFMA-pipe-cyc/seq-step.
// Lane l owns seq l>>4's state at hids (l&15)+16u; A-frags via 8 ds_bpermute
// with loop-invariant indices (source seq (l&15)>>2); gate g of sub-hid u =
// tile 4g+u (static indexing, no cndmasks). Ring: compute wave pre-reduces
// z = h . W_out (4 fma + 4 row-shr DPP) -> zring[2][128][4] f32 (4 KB); loss
// wave reads z directly (no 64-lane reduction, no h ring). Grid 256 blocks
// (4 seqs each) x {compute wave, loss wave}. Sync shell unchanged.

#define CH  128
#define HID 64

typedef __fp16 half8 __attribute__((ext_vector_type(8)));
typedef float  f32x4 __attribute__((ext_vector_type(4)));
typedef int    int4v __attribute__((ext_vector_type(4)));

__device__ __forceinline__ int bperm(int byte_idx, int src) {
  return __builtin_amdgcn_ds_bpermute(byte_idx, src);
}
__device__ __forceinline__ float bpermf(int byte_idx, float src) {
  return __builtin_bit_cast(float, __builtin_amdgcn_ds_bpermute(byte_idx, __builtin_bit_cast(int, src)));
}
__device__ __forceinline__ int packh(float a, float b) {
  return __builtin_bit_cast(int, __builtin_amdgcn_cvt_pkrtz(a, b));
}
__device__ __forceinline__ float frcp(float x) { return __builtin_amdgcn_rcpf(x); }
__device__ __forceinline__ float sigm(float x) { return frcp(1.0f + __expf(-x)); }
__device__ __forceinline__ float tanh_(float x) {
  float e = __expf(2.0f * x);
  return 1.0f - 2.0f * frcp(e + 1.0f);
}
template <int CTRL, int RMASK>
__device__ __forceinline__ float dpp_add(float v) {
  int x = __builtin_amdgcn_update_dpp(0, __builtin_bit_cast(int, v), CTRL, RMASK, 0xF, true);
  return v + __builtin_bit_cast(float, x);
}
__device__ __forceinline__ float dpp_xor1(float v) {  // quad_perm [1,0,3,2]
  int x = __builtin_amdgcn_update_dpp(0, __builtin_bit_cast(int, v), 0xB1, 0xF, 0xF, true);
  return __builtin_bit_cast(float, x);
}
__device__ __forceinline__ float dpp_row_sum(float v) {  // row total lands in lane 15 of each 16-row
  v = dpp_add<0x111, 0xF>(v);
  v = dpp_add<0x112, 0xF>(v);
  v = dpp_add<0x114, 0xF>(v);
  v = dpp_add<0x118, 0xF>(v);
  return v;
}
__device__ __forceinline__ float dpp_wave_sum(float v) {  // total lands in lane 63
  v = dpp_row_sum(v);
  v = dpp_add<0x142, 0xA>(v);   // row_bcast:15
  v = dpp_add<0x143, 0xC>(v);   // row_bcast:31
  return v;
}

__global__ __attribute__((amdgpu_flat_work_group_size(128, 128), amdgpu_waves_per_eu(1, 2)))
void pc_lstm_kernel(const int* __restrict__ inds,
                    const float* __restrict__ p,
                    const float* __restrict__ ls_probs,
                    const float* __restrict__ open_probs,
                    const int* __restrict__ open_slices,
                    const float* __restrict__ open_hx,
                    const float* __restrict__ W_ih,
                    const float* __restrict__ W_hh,
                    const float* __restrict__ b_ih,
                    const float* __restrict__ b_hh,
                    const float* __restrict__ W_out,
                    const float* __restrict__ b_out,
                    const int* __restrict__ n_chunks_p,
                    float* __restrict__ out)
{
  __shared__ float zring[2][CH][4];     // 4 KB: pre-reduced z = h.W_out per (t, seq)
  __shared__ int prod;                  // chunks fully written by wave0
  __shared__ int cons;                  // chunks fully consumed by wave1

  const int tid  = threadIdx.x;
  const int wv   = tid >> 6;           // 0 = compute, 1 = loss
  const int lane = tid & 63;
  const int s    = blockIdx.x;         // 4 sequences per block: 4s .. 4s+3
  const int n_chunks = n_chunks_p[0];
  const int q    = lane >> 4;          // seq-in-block this lane serves
  const int cc   = lane & 15;
  const int sq   = 4 * s + q;          // this lane's global sequence
  const int tb   = inds[sq >> 4] + (sq & 15);
  const float2* p2 = (const float2*)p;
  const int xbase = 4 * (16 * q);      // bperm byte base for per-seq scalars

  if (tid == 0) { prod = 0; cons = 0; }
  __syncthreads();                      // only barrier in the kernel

  if (wv == 0) {
    // ================= compute wave =================
    const int kg = lane >> 4;          // k-group of the A/B fragments

    // B fragments (identical packing to R15, HW-verified): tile t covers
    // preact rows n = 16t + col; k = 32*kc + 8*kg + j.
    half8 Wb[32];
#pragma unroll
    for (int t = 0; t < 16; ++t) {
#pragma unroll
      for (int kc = 0; kc < 2; ++kc) {
        const float* wp = W_hh + (16 * t + cc) * HID + 32 * kc + 8 * kg;
        half8 w;
#pragma unroll
        for (int j = 0; j < 8; ++j) w[j] = (__fp16)wp[j];
        Wb[2 * t + kc] = w;
      }
    }

    // per-(gate, sub-hid) x-weights and bias: hid = cc + 16u
    float wxa[4][4], wxb[4][4], bb[4][4];
#pragma unroll
    for (int g = 0; g < 4; ++g)
#pragma unroll
      for (int u = 0; u < 4; ++u) {
        const int r = g * HID + cc + 16 * u;
        wxa[g][u] = W_ih[2 * r];
        wxb[g][u] = W_ih[2 * r + 1];
        bb[g][u]  = b_ih[r] + b_hh[r];
      }
    float wo[4];
#pragma unroll
    for (int u = 0; u < 4; ++u) wo[u] = W_out[cc + 16 * u];

    // state: lane l holds seq l>>4, hids cc+16u
    float h[4], c[4];
#pragma unroll
    for (int u = 0; u < 4; ++u) {
      h[u] = open_hx[(sq * 2 + 0) * HID + cc + 16 * u];
      c[u] = open_hx[(sq * 2 + 1) * HID + cc + 16 * u];
    }

    // A-frag bperm indices (loop-invariant): row = cc -> source seq cc>>2;
    // word w of a0/a1 pulls the h-pair at hid-offset ((8kg)&15)+2w of slot
    // u = kg>>1 (a0) / 2+(kg>>1) (a1).
    const int qa = cc >> 2;
    int idxA[4];
#pragma unroll
    for (int w = 0; w < 4; ++w)
      idxA[w] = 4 * (16 * qa + ((8 * kg) & 15) + 2 * w);
    const bool kgLow = (kg < 2);
    const f32x4 zero4 = {0.f, 0.f, 0.f, 0.f};

    for (int off = 0; off < n_chunks; ++off) {
      // chunk x data: lane l holds seq l>>4, times cc+16m (m=0..7),
      // base-subtracted (reference: x = p_chunk - p_chunk[...,0,:])
      float xsx[8], xsy[8];
      {
        float2 tmp[8];
        const long cb = (long)tb + (long)off * CH;
#pragma unroll
        for (int m = 0; m < 8; ++m) tmp[m] = p2[cb + cc + 16 * m];
        const float px0 = bpermf(xbase, tmp[0].x);   // seq q's chunk time-0
        const float px1 = bpermf(xbase, tmp[0].y);
#pragma unroll
        for (int m = 0; m < 8; ++m) {
          xsx[m] = tmp[m].x - px0;
          xsy[m] = tmp[m].y - px1;
        }
      }
      while (__hip_atomic_load(&cons, __ATOMIC_ACQUIRE, __HIP_MEMORY_SCOPE_WORKGROUP) + 2 <= off)
        __builtin_amdgcn_s_sleep(8);

      float* zslot = &zring[off & 1][0][0];
#pragma unroll
      for (int m = 0; m < 8; ++m) {
#pragma unroll 1
        for (int tt = 0; tt < 16; ++tt) {
          const int t = 16 * m + tt;
          // ---- A fragments: static crossbar of the 4 seqs' h ----
          const float hx0 = dpp_xor1(h[0]), hx1 = dpp_xor1(h[1]);
          const float hx2 = dpp_xor1(h[2]), hx3 = dpp_xor1(h[3]);
          const int hp0 = packh(h[0], hx0), hp1 = packh(h[1], hx1);
          const int hp2 = packh(h[2], hx2), hp3 = packh(h[3], hx3);
          const int hA = kgLow ? hp0 : hp1;
          const int hB = kgLow ? hp2 : hp3;
          int4v A0, A1;
#pragma unroll
          for (int w = 0; w < 4; ++w) {
            A0[w] = bperm(idxA[w], hA);
            A1[w] = bperm(idxA[w], hB);
          }
          const half8 a0 = __builtin_bit_cast(half8, A0);   // k = 0..31
          const half8 a1 = __builtin_bit_cast(half8, A1);   // k = 32..63

          // ---- per-seq x scalars ----
          const int xi = xbase + 4 * tt;
          const float x0 = bpermf(xi, xsx[m]);
          const float x1 = bpermf(xi, xsy[m]);

          // ---- per-u: 4 tiles (8 MFMA) -> 4 gates -> h[u],c[u] update ----
#pragma unroll
          for (int u = 0; u < 4; ++u) {
            f32x4 e0 = __builtin_amdgcn_mfma_f32_16x16x32_f16(a0, Wb[     2 * u], zero4, 0, 0, 0);
            e0       = __builtin_amdgcn_mfma_f32_16x16x32_f16(a1, Wb[ 1 + 2 * u], e0,    0, 0, 0);
            f32x4 e1 = __builtin_amdgcn_mfma_f32_16x16x32_f16(a0, Wb[ 8 + 2 * u], zero4, 0, 0, 0);
            e1       = __builtin_amdgcn_mfma_f32_16x16x32_f16(a1, Wb[ 9 + 2 * u], e1,    0, 0, 0);
            f32x4 e2 = __builtin_amdgcn_mfma_f32_16x16x32_f16(a0, Wb[16 + 2 * u], zero4, 0, 0, 0);
            e2       = __builtin_amdgcn_mfma_f32_16x16x32_f16(a1, Wb[17 + 2 * u], e2,    0, 0, 0);
            f32x4 e3 = __builtin_amdgcn_mfma_f32_16x16x32_f16(a0, Wb[24 + 2 * u], zero4, 0, 0, 0);
            e3       = __builtin_amdgcn_mfma_f32_16x16x32_f16(a1, Wb[25 + 2 * u], e3,    0, 0, 0);

            const float pa0 = fmaf(x0, wxa[0][u], fmaf(x1, wxb[0][u], e0[0] + bb[0][u]));
            const float pa1 = fmaf(x0, wxa[1][u], fmaf(x1, wxb[1][u], e1[0] + bb[1][u]));
            const float pa2 = fmaf(x0, wxa[2][u], fmaf(x1, wxb[2][u], e2[0] + bb[2][u]));
            const float pa3 = fmaf(x0, wxa[3][u], fmaf(x1, wxb[3][u], e3[0] + bb[3][u]));

            const float ig = sigm(pa0);
            const float fg = sigm(pa1);
            const float gg = tanh_(pa2);
            const float og = sigm(pa3);
            c[u] = fmaf(fg, c[u], ig * gg);
            h[u] = og * tanh_(c[u]);
          }

          // ---- z = h . W_out, reduced within each 16-lane row ----
          float part = h[0] * wo[0];
          part = fmaf(h[1], wo[1], part);
          part = fmaf(h[2], wo[2], part);
          part = fmaf(h[3], wo[3], part);
          part = dpp_row_sum(part);          // z_q at lane 16q+15
          if (cc == 15) zslot[t * 4 + q] = part;
        }
      }
      if (lane == 0)
        __hip_atomic_store(&prod, off + 1, __ATOMIC_RELEASE, __HIP_MEMORY_SCOPE_WORKGROUP);
    }
  } else {
    // ================= loss wave =================
    // lane l serves seq l>>4 (16-way redundant within the row)
    const float bout = b_out[0];
    const int   os   = open_slices[sq];
    const float OL   = __logf(p[2 * os]) + __logf(p[2 * os + 1]);
    const float coef = open_probs[sq] * (2.0f * ls_probs[sq] - 1.0f);

    float S = 1.0f, D = 1.0f, lsum = 0.0f, psum = 0.0f;

    for (int off = 0; off < n_chunks; ++off) {
      // per-chunk log-payoffs: lane l holds seq l>>4, times cc+16m
      float L[8];
      {
        const long cb = (long)tb + (long)off * CH;
#pragma unroll
        for (int m = 0; m < 8; ++m) {
          const float2 t2 = p2[cb + cc + 16 * m];
          L[m] = __logf(t2.x) + __logf(t2.y);
        }
      }
      while (__hip_atomic_load(&prod, __ATOMIC_ACQUIRE, __HIP_MEMORY_SCOPE_WORKGROUP) <= off)
        __builtin_amdgcn_s_sleep(32);

      const float* zs = &zring[off & 1][0][0];
#pragma unroll
      for (int m = 0; m < 8; ++m) {
#pragma unroll 1
        for (int tt = 0; tt < 16; ++tt) {
          const int t = 16 * m + tt;
          const float z  = zs[t * 4 + q];
          const float pr = sigm(z + bout);
          const float Lt = bpermf(xbase + 4 * tt, L[m]);
          const float pn = (t == 0) ? pr : pr * D;
          lsum = fmaf(pn, Lt, lsum);
          psum += pn;
          if (t == 0)           D = S * (1.0f - pr);   // chunk t=0 undiscounted (ref quirk)
          else if (t < CH - 1)  D *= (1.0f - pr);
          else                  S = D;                  // carry excludes (1-p_last)
        }
      }
      if (lane == 0)
        __hip_atomic_store(&cons, off + 1, __ATOMIC_RELEASE, __HIP_MEMORY_SCOPE_WORKGROUP);
    }
    float v = coef * (lsum - OL * psum);
    v = (cc == 0) ? v : 0.0f;            // one contributor per 16-lane row
    v = dpp_wave_sum(v);
    if (lane == 63) atomicAdd(out, v);
  }
}

extern "C" void kernel_launch(void* const* d_in, const int* in_sizes, int n_in,
                              void* d_out, int out_size, void* d_ws, size_t ws_size,
                              hipStream_t stream) {
  (void)hipMemsetAsync(d_out, 0, sizeof(float), stream);

  pc_lstm_kernel<<<dim3(256), dim3(128), 0, stream>>>(
      (const int*)d_in[0],    // inds
      (const float*)d_in[1],  // p
      (const float*)d_in[2],  // ls_probs
      (const float*)d_in[3],  // open_probs
      (const int*)d_in[4],    // open_slices
      (const float*)d_in[5],  // open_hx
      (const float*)d_in[6],  // W_ih
      (const float*)d_in[7],  // W_hh
      (const float*)d_in[8],  // b_ih
      (const float*)d_in[9],  // b_hh
      (const float*)d_in[10], // W_out
      (const float*)d_in[11], // b_out
      (const int*)d_in[12],   // n_chunks
      (float*)d_out);
}

// Round 5
// 9394.395 us; speedup vs baseline: 1.1175x; 1.1175x over previous
//
#include <hip/hip_runtime.h>

// PositionCloser round 18 = R17 resubmit (R4 bench was an infra failure:
// "container failed twice", no compile error / absmax / counters; sync shell
// is byte-identical to the passing R15, so no hang vector in the kernel).
//
// R17 theory (unchanged): R15 accounting: 1030 cyc/step = 512 MFMA-pipe
// (MfmaUtil 49.4% exact) + ~520 exposed. Fix: gates i,f stay on MFMA
// (tiles 0-7, 16 MFMAs = 256 pipe cyc); gates g,o move to v_dot2_f32_f16 on
// the VALU pipe (per-lane hid=lane, 64 dot2s in 4 interleaved acc chains),
// h-pair broadcast via 32 uniform-index ds_bpermute (same-source =
// broadcast, conflict-free). MFMA pipe and VALU exec run concurrently
// (m114); dot2 issue hides under the MFMA drain. Shell/sync/loss = R15.

#define CH  128
#define HID 64

typedef __fp16 half8 __attribute__((ext_vector_type(8)));
typedef __fp16 half2v __attribute__((ext_vector_type(2)));
typedef float  f32x4 __attribute__((ext_vector_type(4)));
typedef int    int4v __attribute__((ext_vector_type(4)));

__device__ __forceinline__ float rlf(float v, int l) {
  return __builtin_bit_cast(float, __builtin_amdgcn_readlane(__builtin_bit_cast(int, v), l));
}
__device__ __forceinline__ int packh(float a, float b) {
  return __builtin_bit_cast(int, __builtin_amdgcn_cvt_pkrtz(a, b));
}
__device__ __forceinline__ float frcp(float x) { return __builtin_amdgcn_rcpf(x); }
__device__ __forceinline__ float sigm(float x) { return frcp(1.0f + __expf(-x)); }
__device__ __forceinline__ float tanh_(float x) {
  float e = __expf(2.0f * x);
  return 1.0f - 2.0f * frcp(e + 1.0f);
}
template <int CTRL, int RMASK>
__device__ __forceinline__ float dpp_add(float v) {
  int x = __builtin_amdgcn_update_dpp(0, __builtin_bit_cast(int, v), CTRL, RMASK, 0xF, true);
  return v + __builtin_bit_cast(float, x);
}
__device__ __forceinline__ float dpp_xor1(float v) {  // quad_perm [1,0,3,2]
  int x = __builtin_amdgcn_update_dpp(0, __builtin_bit_cast(int, v), 0xB1, 0xF, 0xF, true);
  return __builtin_bit_cast(float, x);
}
__device__ __forceinline__ float dpp_wave_sum(float v) {  // total lands in lane 63
  v = dpp_add<0x111, 0xF>(v);
  v = dpp_add<0x112, 0xF>(v);
  v = dpp_add<0x114, 0xF>(v);
  v = dpp_add<0x118, 0xF>(v);
  v = dpp_add<0x142, 0xA>(v);   // row_bcast:15
  v = dpp_add<0x143, 0xC>(v);   // row_bcast:31
  return v;
}

__global__ __attribute__((amdgpu_flat_work_group_size(128, 128), amdgpu_waves_per_eu(2, 2)))
void pc_lstm_kernel(const int* __restrict__ inds,
                    const float* __restrict__ p,
                    const float* __restrict__ ls_probs,
                    const float* __restrict__ open_probs,
                    const int* __restrict__ open_slices,
                    const float* __restrict__ open_hx,
                    const float* __restrict__ W_ih,
                    const float* __restrict__ W_hh,
                    const float* __restrict__ b_ih,
                    const float* __restrict__ b_hh,
                    const float* __restrict__ W_out,
                    const float* __restrict__ b_out,
                    const int* __restrict__ n_chunks_p,
                    float* __restrict__ out)
{
  __shared__ __fp16 ring[2][CH][HID];   // 32 KB: h history for the lagged loss
  __shared__ int prod;                  // chunks fully written by wave0
  __shared__ int cons;                  // chunks fully consumed by wave1

  const int tid  = threadIdx.x;
  const int wv   = tid >> 6;           // 0 = compute, 1 = loss
  const int lane = tid & 63;
  const int s    = blockIdx.x;         // one sequence per block
  const int n_chunks = n_chunks_p[0];
  const int tbase = inds[s >> 4] + (s & 15);
  const float2* p2 = (const float2*)p;

  if (tid == 0) { prod = 0; cons = 0; }
  __syncthreads();                      // only barrier in the kernel

  if (wv == 0) {
    // ================= compute wave =================
    const int kg = lane >> 4;          // k-group (A/B fragment k-chunk index)
    const int cc = lane & 15;          // column within a 16-wide N-tile

    // MFMA B fragments for gates i,f only (tiles 0..7; HW-verified packing):
    // tile t covers preact rows n = 16t + col; k = 32*kc + 8*kg + j.
    half8 Wb[16];
#pragma unroll
    for (int t = 0; t < 8; ++t) {
#pragma unroll
      for (int kc = 0; kc < 2; ++kc) {
        const float* wp = W_hh + (16 * t + cc) * HID + 32 * kc + 8 * kg;
        half8 w;
#pragma unroll
        for (int j = 0; j < 8; ++j) w[j] = (__fp16)wp[j];
        Wb[2 * t + kc] = w;
      }
    }

    // VALU dot2 weights for gates g,o: lane owns row hid=lane, packed pairs.
    half2v Wg[32], Wo[32];
    {
      const float2* rg = (const float2*)(W_hh + (2 * HID + lane) * HID);
      const float2* ro = (const float2*)(W_hh + (3 * HID + lane) * HID);
#pragma unroll
      for (int j = 0; j < 32; ++j) {
        float2 vg = rg[j], vo = ro[j];
        Wg[j] = __builtin_bit_cast(half2v, packh(vg.x, vg.y));
        Wo[j] = __builtin_bit_cast(half2v, packh(vo.x, vo.y));
      }
    }

    float wxa[4], wxb[4], bb[4];
#pragma unroll
    for (int g = 0; g < 4; ++g) {
      const int r = g * HID + lane;
      wxa[g] = W_ih[2 * r];
      wxb[g] = W_ih[2 * r + 1];
      bb[g]  = b_ih[r] + b_hh[r];
    }
    float h = open_hx[(s * 2 + 0) * HID + lane];
    float c = open_hx[(s * 2 + 1) * HID + lane];

    // bpermute byte-indices (loop-invariant):
    // A-frags: a0 word w pulls hp from lane 8*kg+2w; a1 from lane 32+8*kg+2w.
    int ia0[4], ia1[4];
#pragma unroll
    for (int w = 0; w < 4; ++w) {
      ia0[w] = 4 * (8 * kg + 2 * w);
      ia1[w] = 4 * (32 + 8 * kg + 2 * w);
    }

    const bool u1 = (lane & 16) != 0;  // bit0 of u = lane>>4
    const bool u2 = (lane & 32) != 0;  // bit1 of u
    const f32x4 zero4 = {0.f, 0.f, 0.f, 0.f};

    float2 curA = p2[tbase + lane];
    float2 curB = p2[tbase + HID + lane];
    float2 nxtA = curA, nxtB = curB;

    for (int off = 0; off < n_chunks; ++off) {
      if (off) { curA = nxtA; curB = nxtB; }
      const float px0 = rlf(curA.x, 0);
      const float px1 = rlf(curA.y, 0);
      float2 xA, xB;                       // pre-subtracted chunk base
      xA.x = curA.x - px0; xA.y = curA.y - px1;
      xB.x = curB.x - px0; xB.y = curB.y - px1;
      if (off + 1 < n_chunks) {
        const int nb = tbase + (off + 1) * CH;
        nxtA = p2[nb + lane];
        nxtB = p2[nb + HID + lane];
      }
      while (__hip_atomic_load(&cons, __ATOMIC_ACQUIRE, __HIP_MEMORY_SCOPE_WORKGROUP) + 2 <= off)
        __builtin_amdgcn_s_sleep(8);

      __fp16* slot = &ring[off & 1][0][0];
#pragma unroll
      for (int hf = 0; hf < 2; ++hf) {
        const float xcx = hf ? xB.x : xA.x;
        const float xcy = hf ? xB.y : xA.y;
#pragma unroll 1
        for (int tl = 0; tl < 64; ++tl) {
          // ---- packed h pairs (even lane 2j holds (h_2j, h_2j+1)) ----
          const int hp = packh(h, dpp_xor1(h));

          // ---- MFMA A fragments via crossbar ----
          int4v A0, A1;
#pragma unroll
          for (int w = 0; w < 4; ++w) {
            A0[w] = __builtin_amdgcn_ds_bpermute(ia0[w], hp);
            A1[w] = __builtin_amdgcn_ds_bpermute(ia1[w], hp);
          }
          const half8 a0 = __builtin_bit_cast(half8, A0);   // k = 0..31
          const half8 a1 = __builtin_bit_cast(half8, A1);   // k = 32..63

          const float x0 = rlf(xcx, tl);
          const float x1 = rlf(xcy, tl);

          // ---- gates i,f on the MFMA pipe (16 MFMAs, tiles 0..7) ----
          f32x4 q0 = __builtin_amdgcn_mfma_f32_16x16x32_f16(a0, Wb[0],  zero4, 0, 0, 0);
          q0       = __builtin_amdgcn_mfma_f32_16x16x32_f16(a1, Wb[1],  q0,    0, 0, 0);
          f32x4 q1 = __builtin_amdgcn_mfma_f32_16x16x32_f16(a0, Wb[2],  zero4, 0, 0, 0);
          q1       = __builtin_amdgcn_mfma_f32_16x16x32_f16(a1, Wb[3],  q1,    0, 0, 0);
          f32x4 q2 = __builtin_amdgcn_mfma_f32_16x16x32_f16(a0, Wb[4],  zero4, 0, 0, 0);
          q2       = __builtin_amdgcn_mfma_f32_16x16x32_f16(a1, Wb[5],  q2,    0, 0, 0);
          f32x4 q3 = __builtin_amdgcn_mfma_f32_16x16x32_f16(a0, Wb[6],  zero4, 0, 0, 0);
          q3       = __builtin_amdgcn_mfma_f32_16x16x32_f16(a1, Wb[7],  q3,    0, 0, 0);
          f32x4 r0 = __builtin_amdgcn_mfma_f32_16x16x32_f16(a0, Wb[8],  zero4, 0, 0, 0);
          r0       = __builtin_amdgcn_mfma_f32_16x16x32_f16(a1, Wb[9],  r0,    0, 0, 0);
          f32x4 r1 = __builtin_amdgcn_mfma_f32_16x16x32_f16(a0, Wb[10], zero4, 0, 0, 0);
          r1       = __builtin_amdgcn_mfma_f32_16x16x32_f16(a1, Wb[11], r1,    0, 0, 0);
          f32x4 r2 = __builtin_amdgcn_mfma_f32_16x16x32_f16(a0, Wb[12], zero4, 0, 0, 0);
          r2       = __builtin_amdgcn_mfma_f32_16x16x32_f16(a1, Wb[13], r2,    0, 0, 0);
          f32x4 r3 = __builtin_amdgcn_mfma_f32_16x16x32_f16(a0, Wb[14], zero4, 0, 0, 0);
          r3       = __builtin_amdgcn_mfma_f32_16x16x32_f16(a1, Wb[15], r3,    0, 0, 0);

          // ---- gates g,o on the VALU pipe (64 dot2s, 4 interleaved chains) ----
          float gA = fmaf(x0, wxa[2], bb[2]);
          float gB = x1 * wxb[2];
          float oA = fmaf(x0, wxa[3], bb[3]);
          float oB = x1 * wxb[3];
#pragma unroll
          for (int j = 0; j < 16; ++j) {
            const half2v hb0 = __builtin_bit_cast(half2v,
                __builtin_amdgcn_ds_bpermute(8 * (2 * j), hp));      // pairs 2j
            const half2v hb1 = __builtin_bit_cast(half2v,
                __builtin_amdgcn_ds_bpermute(8 * (2 * j + 1), hp));  // pairs 2j+1
            gA = __builtin_amdgcn_fdot2(hb0, Wg[2 * j],     gA, false);
            oA = __builtin_amdgcn_fdot2(hb0, Wo[2 * j],     oA, false);
            gB = __builtin_amdgcn_fdot2(hb1, Wg[2 * j + 1], gB, false);
            oB = __builtin_amdgcn_fdot2(hb1, Wo[2 * j + 1], oB, false);
          }

          // ---- extract i,f preacts (same select as R15, absmax-0 verified) ----
          const float si01 = u1 ? q1[0] : q0[0];
          const float si23 = u1 ? q3[0] : q2[0];
          const float di   = u2 ? si23 : si01;
          const float sf01 = u1 ? r1[0] : r0[0];
          const float sf23 = u1 ? r3[0] : r2[0];
          const float df   = u2 ? sf23 : sf01;
          const float pai = fmaf(x0, wxa[0], fmaf(x1, wxb[0], di + bb[0]));
          const float paf = fmaf(x0, wxa[1], fmaf(x1, wxb[1], df + bb[1]));

          const float ig = sigm(pai);
          const float fg = sigm(paf);
          const float gg = tanh_(gA + gB);
          const float og = sigm(oA + oB);
          c = fmaf(fg, c, ig * gg);
          h = og * tanh_(c);

          const int tt = hf * 64 + tl;
          slot[tt * HID + lane] = (__fp16)h;   // ds_write_b16 (ring, off chain)
        }
      }
      if (lane == 0)
        __hip_atomic_store(&prod, off + 1, __ATOMIC_RELEASE, __HIP_MEMORY_SCOPE_WORKGROUP);
    }
  } else {
    // ================= loss wave =================
    const float wo   = W_out[lane];
    const float bout = b_out[0];
    const int   os   = open_slices[s];
    const float OL   = __logf(p[2 * os]) + __logf(p[2 * os + 1]);
    const float coef = open_probs[s] * (2.0f * ls_probs[s] - 1.0f);

    float S = 1.0f, D = 1.0f, lsum = 0.0f, psum = 0.0f;

    for (int off = 0; off < n_chunks; ++off) {
      const int cb = tbase + off * CH;
      const float2 cA = p2[cb + lane];
      const float2 cB = p2[cb + HID + lane];
      const float LA = __logf(cA.x) + __logf(cA.y);
      const float LB = __logf(cB.x) + __logf(cB.y);

      while (__hip_atomic_load(&prod, __ATOMIC_ACQUIRE, __HIP_MEMORY_SCOPE_WORKGROUP) <= off)
        __builtin_amdgcn_s_sleep(32);

      const __fp16* slot = &ring[off & 1][0][0];
#pragma unroll 1
      for (int tt = 0; tt < CH; ++tt) {
        const float hv = (float)slot[tt * HID + lane];
        const float z  = rlf(dpp_wave_sum(hv * wo), 63);
        const float pr = sigm(z + bout);
        const float Lt = (tt < 64) ? rlf(LA, tt) : rlf(LB, tt - 64);
        const float pn = (tt == 0) ? pr : pr * D;
        lsum = fmaf(pn, Lt, lsum);
        psum += pn;
        if (tt == 0)           D = S * (1.0f - pr);   // chunk t=0 undiscounted (ref quirk)
        else if (tt < CH - 1)  D *= (1.0f - pr);
        else                   S = D;                  // carry excludes (1-p_last)
      }
      if (lane == 0)
        __hip_atomic_store(&cons, off + 1, __ATOMIC_RELEASE, __HIP_MEMORY_SCOPE_WORKGROUP);
    }
    if (lane == 0) atomicAdd(out, coef * (lsum - OL * psum));
  }
}

extern "C" void kernel_launch(void* const* d_in, const int* in_sizes, int n_in,
                              void* d_out, int out_size, void* d_ws, size_t ws_size,
                              hipStream_t stream) {
  (void)hipMemsetAsync(d_out, 0, sizeof(float), stream);

  pc_lstm_kernel<<<dim3(1024), dim3(128), 0, stream>>>(
      (const int*)d_in[0],    // inds
      (const float*)d_in[1],  // p
      (const float*)d_in[2],  // ls_probs
      (const float*)d_in[3],  // open_probs
      (const int*)d_in[4],    // open_slices
      (const float*)d_in[5],  // open_hx
      (const float*)d_in[6],  // W_ih
      (const float*)d_in[7],  // W_hh
      (const float*)d_in[8],  // b_ih
      (const float*)d_in[9],  // b_hh
      (const float*)d_in[10], // W_out
      (const float*)d_in[11], // b_out
      (const int*)d_in[12],   // n_chunks
      (float*)d_out);
}